// Round 3
// baseline (75.139 us; speedup 1.0000x reference)
//
#include <hip/hip_runtime.h>
#include <math.h>

// VanillaSFNN: B=1024, T=1024, H=256, IN=2, OUT=2, DECAY=0.8
// Round 3: 2 independent packed-f32 chains per lane (4 hidden units/lane),
//          block=64 (1 wave), grid=1024 (1 block per batch).
//   - x[b] staged PLAIN in LDS (8KB, {x0,x1} per step): conflict-free writes,
//     one broadcast ds_read_b128 per 2 steps shared by both chains
//   - VOP3P op_sel broadcasts x0/x1 from the pair to both packed halves:
//     no duplication movs, no duplicated LDS layout
//   - 2-ahead prefetch (~200cy) hides LDS latency for the single wave/SIMD
//   - v-path arithmetic identical (per half) to reference f32 op order;
//     spike decisions bit-exact. Spikes accumulated negated so reset +
//     S-update stay packed (sign-symmetric ops round identically).

constexpr int T_STEPS = 1024;
constexpr int HIDDEN  = 256;
constexpr int BLK     = 64;    // one wave; lane covers h, h+64, h+128, h+192

typedef float f32x2 __attribute__((ext_vector_type(2)));
typedef float f32x4 __attribute__((ext_vector_type(4)));

static __device__ __forceinline__ f32x2 pk_mul(f32x2 a, f32x2 b) {
    f32x2 d; asm("v_pk_mul_f32 %0, %1, %2" : "=v"(d) : "v"(a), "v"(b)); return d;
}
static __device__ __forceinline__ f32x2 pk_add(f32x2 a, f32x2 b) {
    f32x2 d; asm("v_pk_add_f32 %0, %1, %2" : "=v"(d) : "v"(a), "v"(b)); return d;
}
static __device__ __forceinline__ f32x2 pk_fma(f32x2 a, f32x2 b, f32x2 c) {
    f32x2 d; asm("v_pk_fma_f32 %0, %1, %2, %3" : "=v"(d) : "v"(a), "v"(b), "v"(c)); return d;
}
// both packed halves get word0 of x (x0); w is normal packed
static __device__ __forceinline__ f32x2 pk_mul_bc0(f32x2 x, f32x2 w) {
    f32x2 d; asm("v_pk_mul_f32 %0, %1, %2 op_sel:[0,0] op_sel_hi:[0,1]"
                 : "=v"(d) : "v"(x), "v"(w)); return d;
}
// both packed halves get word1 of x (x1); w is normal packed
static __device__ __forceinline__ f32x2 pk_mul_bc1(f32x2 x, f32x2 w) {
    f32x2 d; asm("v_pk_mul_f32 %0, %1, %2 op_sel:[1,0] op_sel_hi:[1,1]"
                 : "=v"(d) : "v"(x), "v"(w)); return d;
}

__global__ __launch_bounds__(BLK) void sfnn_ilp_kernel(
    const float* __restrict__ x_seq,   // [B, T, 2]
    const float* __restrict__ W_in,    // [H, 2]
    const float* __restrict__ b_in,    // [H]
    const float* __restrict__ W_out,   // [2, H]
    const float* __restrict__ b_out,   // [2]
    const float* __restrict__ tau_m,   // [H]
    float* __restrict__ out)           // [B, 2]
{
    __shared__ f32x4 xs[T_STEPS / 2];  // 8 KB: plain x[b], 2 steps per entry

    const int b   = blockIdx.x;
    const int tid = threadIdx.x;

    // --- stage x[b] into LDS (coalesced float4, stride-16B: conflict-free) ---
    const float4* __restrict__ xg =
        reinterpret_cast<const float4*>(x_seq) + (size_t)b * (T_STEPS / 2);
    float4* __restrict__ xsw = reinterpret_cast<float4*>(xs);
    #pragma unroll
    for (int k = 0; k < (T_STEPS / 2) / BLK; ++k)
        xsw[tid + k * BLK] = xg[tid + k * BLK];

    // --- per-lane constants: chain A = (tid, tid+64), chain B = (tid+128, tid+192) ---
    const int hA0 = tid, hA1 = tid + 64, hB0 = tid + 128, hB1 = tid + 192;
    f32x2 w0A, w1A, biA, alA, beA, w0B, w1B, biB, alB, beB, c08;
    w0A.x = W_in[2*hA0];   w0A.y = W_in[2*hA1];
    w1A.x = W_in[2*hA0+1]; w1A.y = W_in[2*hA1+1];
    biA.x = b_in[hA0];     biA.y = b_in[hA1];
    w0B.x = W_in[2*hB0];   w0B.y = W_in[2*hB1];
    w1B.x = W_in[2*hB0+1]; w1B.y = W_in[2*hB1+1];
    biB.x = b_in[hB0];     biB.y = b_in[hB1];
    alA.x = 1.0f / (1.0f + expf(-tau_m[hA0]));
    alA.y = 1.0f / (1.0f + expf(-tau_m[hA1]));
    alB.x = 1.0f / (1.0f + expf(-tau_m[hB0]));
    alB.y = 1.0f / (1.0f + expf(-tau_m[hB1]));
    beA.x = 1.0f - alA.x;  beA.y = 1.0f - alA.y;
    beB.x = 1.0f - alB.x;  beB.y = 1.0f - alB.y;
    c08.x = 0.8f;          c08.y = 0.8f;

    __syncthreads();

    f32x2 vA = {0.0f, 0.0f}, vB = {0.0f, 0.0f};
    f32x2 SnA = {0.0f, 0.0f}, SnB = {0.0f, 0.0f};   // negated decayed spike sums

    // one LIF step for both chains; xp = {x0(t), x1(t)}
    auto step = [&](f32x2 xp) {
        // cur = (x0*w0 + x1*w1) + b_in   (reference op order per half)
        f32x2 curA = pk_add(pk_add(pk_mul_bc0(xp, w0A), pk_mul_bc1(xp, w1A)), biA);
        f32x2 curB = pk_add(pk_add(pk_mul_bc0(xp, w0B), pk_mul_bc1(xp, w1B)), biB);
        // v = v*alpha + (1-alpha)*cur    (reference op order per half)
        vA = pk_add(pk_mul(vA, alA), pk_mul(beA, curA));
        vB = pk_add(pk_mul(vB, alB), pk_mul(beB, curB));
        // negated spike: -1 if v >= 1 else 0
        f32x2 spA, spB;
        spA.x = (vA.x >= 1.0f) ? -1.0f : 0.0f;
        spA.y = (vA.y >= 1.0f) ? -1.0f : 0.0f;
        spB.x = (vB.x >= 1.0f) ? -1.0f : 0.0f;
        spB.y = (vB.y >= 1.0f) ? -1.0f : 0.0f;
        vA = pk_add(vA, spA);              // soft reset
        vB = pk_add(vB, spB);
        SnA = pk_fma(c08, SnA, spA);       // Sn = 0.8*Sn - spike
        SnB = pk_fma(c08, SnB, spB);
    };

    // --- main loop: 2 steps per f32x4, prefetch 2 entries (4 steps) ahead ---
    f32x4 xa = xs[0];
    f32x4 xb = xs[1];
    #pragma unroll 2
    for (int i = 0; i < T_STEPS / 2 - 2; ++i) {
        f32x4 xc = xs[i + 2];
        step(__builtin_shufflevector(xa, xa, 0, 1));
        step(__builtin_shufflevector(xa, xa, 2, 3));
        xa = xb; xb = xc;
    }
    step(__builtin_shufflevector(xa, xa, 0, 1));
    step(__builtin_shufflevector(xa, xa, 2, 3));
    step(__builtin_shufflevector(xb, xb, 0, 1));
    step(__builtin_shufflevector(xb, xb, 2, 3));

    // --- project decayed spike sums onto W_out, wave-reduce, write out ---
    const float SAx = -SnA.x, SAy = -SnA.y, SBx = -SnB.x, SBy = -SnB.y;
    const float* __restrict__ Wo0 = W_out;
    const float* __restrict__ Wo1 = W_out + HIDDEN;
    float r0 = SAx * Wo0[hA0] + SAy * Wo0[hA1] + SBx * Wo0[hB0] + SBy * Wo0[hB1];
    float r1 = SAx * Wo1[hA0] + SAy * Wo1[hA1] + SBx * Wo1[hB0] + SBy * Wo1[hB1];
    #pragma unroll
    for (int off = 32; off > 0; off >>= 1) {
        r0 += __shfl_xor(r0, off, 64);
        r1 += __shfl_xor(r1, off, 64);
    }
    if (tid == 0) {
        const float geo = 5.0f;   // sum_{k=0}^{1023} 0.8^k rounds to 5.0f
        out[2 * b]     = r0 + b_out[0] * geo;
        out[2 * b + 1] = r1 + b_out[1] * geo;
    }
}

extern "C" void kernel_launch(void* const* d_in, const int* in_sizes, int n_in,
                              void* d_out, int out_size, void* d_ws, size_t ws_size,
                              hipStream_t stream) {
    const float* x_seq = (const float*)d_in[0];
    const float* W_in  = (const float*)d_in[1];
    const float* b_in  = (const float*)d_in[2];
    const float* W_out = (const float*)d_in[3];
    const float* b_out = (const float*)d_in[4];
    const float* tau_m = (const float*)d_in[5];
    float* out = (float*)d_out;

    sfnn_ilp_kernel<<<dim3(1024), dim3(BLK), 0, stream>>>(
        x_seq, W_in, b_in, W_out, b_out, tau_m, out);
}

// Round 4
// 74.222 us; speedup vs baseline: 1.0123x; 1.0123x over previous
//
#include <hip/hip_runtime.h>
#include <math.h>

// VanillaSFNN: B=1024, T=1024, H=256, IN=2, OUT=2, DECAY=0.8
// Round 4: back to SCALAR f32 (v_pk_*_f32 is not double-rate on CDNA — it
// issues over 4 cy, so packing gains nothing and costs wave-parallelism).
// Config: 1 block/batch, block=256 (1 thread per hidden unit, 4 waves/SIMD
// chip-wide), x[b] in LDS, register prefetch distance 2 entries (4 steps),
// unroll 8 steps, shuffle epilogue. Per-step math identical to R1 (bit-exact
// vs numpy reference).

constexpr int T_STEPS = 1024;
constexpr int HIDDEN  = 256;

__global__ __launch_bounds__(256) void sfnn_sc_kernel(
    const float* __restrict__ x_seq,   // [B, T, 2]
    const float* __restrict__ W_in,    // [H, 2]
    const float* __restrict__ b_in,    // [H]
    const float* __restrict__ W_out,   // [2, H]
    const float* __restrict__ b_out,   // [2]
    const float* __restrict__ tau_m,   // [H]
    float* __restrict__ out)           // [B, 2]
{
    __shared__ float4 xs[T_STEPS / 2];   // 8 KB: x[b], one float4 = 2 steps
    __shared__ float  red[8];            // cross-wave epilogue partials

    const int b   = blockIdx.x;
    const int tid = threadIdx.x;

    // --- stage x[b] into LDS (coalesced float4) ---
    const float4* __restrict__ xg =
        reinterpret_cast<const float4*>(x_seq) + (size_t)b * (T_STEPS / 2);
    xs[tid]          = xg[tid];
    xs[tid + HIDDEN] = xg[tid + HIDDEN];

    // --- per-hidden constants (global loads overlap the staging) ---
    const float w0  = W_in[2 * tid];
    const float w1  = W_in[2 * tid + 1];
    const float bi  = b_in[tid];
    const float al  = 1.0f / (1.0f + expf(-tau_m[tid]));
    const float be  = 1.0f - al;
    const float wo0 = W_out[tid];            // epilogue weights, hoisted
    const float wo1 = W_out[HIDDEN + tid];

    __syncthreads();

    float v = 0.0f;
    float S = 0.0f;

    // one LIF step; arithmetic order matches the reference exactly
    #define LIF_STEP(X0, X1)                                                  \
        {                                                                     \
            float cur = __fadd_rn(__fadd_rn(__fmul_rn((X0), w0),              \
                                            __fmul_rn((X1), w1)), bi);        \
            v = __fadd_rn(__fmul_rn(v, al), __fmul_rn(be, cur));              \
            float sp = (v >= 1.0f) ? 1.0f : 0.0f;                             \
            v -= sp;                                                          \
            S = fmaf(0.8f, S, sp);                                            \
        }

    // --- main loop: 2 steps per entry, prefetch 2 entries (4 steps) ahead ---
    float4 p0 = xs[0];
    float4 p1 = xs[1];
    #pragma unroll 4
    for (int i = 0; i < T_STEPS / 2 - 2; ++i) {
        const float4 nx = xs[i + 2];
        LIF_STEP(p0.x, p0.y)
        LIF_STEP(p0.z, p0.w)
        p0 = p1; p1 = nx;
    }
    LIF_STEP(p0.x, p0.y)
    LIF_STEP(p0.z, p0.w)
    LIF_STEP(p1.x, p1.y)
    LIF_STEP(p1.z, p1.w)
    #undef LIF_STEP

    // --- epilogue: project S onto W_out, wave shuffle-reduce, combine ---
    float r0 = S * wo0;
    float r1 = S * wo1;
    #pragma unroll
    for (int off = 32; off > 0; off >>= 1) {
        r0 += __shfl_xor(r0, off, 64);
        r1 += __shfl_xor(r1, off, 64);
    }
    const int wave = tid >> 6;
    if ((tid & 63) == 0) {
        red[2 * wave]     = r0;
        red[2 * wave + 1] = r1;
    }
    __syncthreads();
    if (tid == 0) {
        const float geo = 5.0f;   // sum_{k=0}^{1023} 0.8^k rounds to 5.0f
        float o0 = (red[0] + red[2]) + (red[4] + red[6]);
        float o1 = (red[1] + red[3]) + (red[5] + red[7]);
        out[2 * b]     = o0 + b_out[0] * geo;
        out[2 * b + 1] = o1 + b_out[1] * geo;
    }
}

extern "C" void kernel_launch(void* const* d_in, const int* in_sizes, int n_in,
                              void* d_out, int out_size, void* d_ws, size_t ws_size,
                              hipStream_t stream) {
    const float* x_seq = (const float*)d_in[0];
    const float* W_in  = (const float*)d_in[1];
    const float* b_in  = (const float*)d_in[2];
    const float* W_out = (const float*)d_in[3];
    const float* b_out = (const float*)d_in[4];
    const float* tau_m = (const float*)d_in[5];
    float* out = (float*)d_out;

    sfnn_sc_kernel<<<dim3(1024), dim3(256), 0, stream>>>(
        x_seq, W_in, b_in, W_out, b_out, tau_m, out);
}